// Round 12
// baseline (154.499 us; speedup 1.0000x reference)
//
#include <hip/hip_runtime.h>

typedef unsigned short u16;
typedef float f32x4 __attribute__((ext_vector_type(4)));
typedef __bf16 bf16x8 __attribute__((ext_vector_type(8)));
typedef unsigned short u16x8 __attribute__((ext_vector_type(8)));
typedef unsigned short u16x4 __attribute__((ext_vector_type(4)));

#define DEV static __device__ __forceinline__

// padded row stride for the qkv intermediate (breaks pow-2 L2-set/channel camping)
#define QS 16448

DEV u16 f2bf(float f) {
  unsigned int u = __float_as_uint(f);
  u += 0x7FFFu + ((u >> 16) & 1u);   // round-to-nearest-even
  return (u16)(u >> 16);
}
DEV float bf2f(u16 h) { return __uint_as_float(((unsigned int)h) << 16); }

// async global->LDS, 16B per lane. LDS dest = wave-uniform base + lane*16.
DEV void gload_lds16(const void* g, void* l) {
  __builtin_amdgcn_global_load_lds(
      (__attribute__((address_space(1))) void*)(unsigned long long)g,
      (__attribute__((address_space(3))) void*)l, 16, 0, 0);
}

// ---------------------------------------------------------------------------
// K0b: convert w_qkv fp32 -> bf16 (plain row-major [576][192])
__global__ __launch_bounds__(256) void convert_w_kernel(
    const float* __restrict__ in, u16* __restrict__ out, int n) {
  int i = blockIdx.x * 256 + threadIdx.x;
  if (i < n) out[i] = f2bf(in[i]);
}

// ---------------------------------------------------------------------------
// Streaming transpose x [b][192][16384] fp32 -> Xt [b][16384][192] bf16.
// 64x64 LDS tiles; input read 256B-coalesced, output 128B segments at a
// 384 B (non-pow-2, L2-set-rich) stride.
__global__ __launch_bounds__(256) void transpose_f32_kernel(
    const float* __restrict__ in, u16* __restrict__ out) {
  __shared__ u16 ls[64][66];
  const int b = blockIdx.z;
  const int c0 = blockIdx.x * 64, r0 = blockIdx.y * 64;
  const float* ip = in + (size_t)b * 192 * 16384;
  u16* op = out + (size_t)b * 16384 * 192;
  const int t = threadIdx.x;
  const int rr = t >> 4, cg = t & 15;
#pragma unroll
  for (int i = 0; i < 4; ++i) {
    const int r = i * 16 + rr;
    const f32x4 v = *(const f32x4*)(ip + (size_t)(r0 + r) * 16384 + c0 + cg * 4);
    ls[r][cg * 4 + 0] = f2bf(v.x);
    ls[r][cg * 4 + 1] = f2bf(v.y);
    ls[r][cg * 4 + 2] = f2bf(v.z);
    ls[r][cg * 4 + 3] = f2bf(v.w);
  }
  __syncthreads();
  const int lane = t & 63, w = t >> 6;
#pragma unroll
  for (int i = 0; i < 16; ++i) {
    const int c = i * 4 + w;
    op[(size_t)(c0 + c) * 192 + r0 + lane] = ls[lane][c];
  }
}

// ---------------------------------------------------------------------------
// qkv GEMM, NO-LOOP small-block full-K. C[j][m] = sum_k Xt[m][k]*Wq[j][k].
// One block = 64 px x 64 ch, full K=192, grid 9216 (m-major, j-fastest,
// XCD-chunk swizzle -> the 9 j-blocks of an A-panel share one XCD L2).
// Block: stage sA 24 KB (24 gload_lds, pre-swizzled src) + per-wave sB
// 6 KB (16 ch), vmcnt(0)+barrier, then 30 ds_read + 24 MFMA per wave,
// restage C into the dead sB, 2 coalesced 128 B-segment stores.
// LDS 48 KB -> 3 blocks/CU; no j-loop, cross-block overlap does the rest.
__global__ __launch_bounds__(256, 3) void gemm_xt_kernel(
    const u16* __restrict__ Xt, const u16* __restrict__ W,
    u16* __restrict__ C, int nwg) {
  __shared__ __align__(16) char smem[49152];
  char* sA = smem;                            // [64][384B] swizzled
  const int tid = threadIdx.x, wave = tid >> 6, lane = tid & 63;
  char* sBw = smem + 24576 + wave * 6144;     // wave-private 16 ch

  const int p = blockIdx.x;
  const int id = (p & 7) * (nwg >> 3) + (p >> 3);
  const int j = id % 9;
  const int t = id / 9;
  const int m0 = (t & 255) * 64, b = t >> 8;

  const char* Ab = (const char*)(Xt + ((size_t)b * 16384 + m0) * 192);
  const char* Bb = (const char*)(W + (size_t)(j * 64 + wave * 16) * 192);

  // stage A: 24 chunks of 1 KB, 6 per wave
#pragma unroll
  for (int i = 0; i < 6; ++i) {
    const int c = i * 4 + wave;
    const int d = c * 1024 + lane * 16;
    const int row = d / 384, inrow = d - row * 384;
    gload_lds16(Ab + row * 384 + (inrow ^ ((row & 7) << 4)), sA + c * 1024);
  }
  // stage wave-private B: 6 chunks
#pragma unroll
  for (int i = 0; i < 6; ++i) {
    const int d = i * 1024 + lane * 16;
    const int row = d / 384, inrow = d - row * 384;
    gload_lds16(Bb + row * 384 + (inrow ^ ((row & 7) << 4)), sBw + i * 1024);
  }
  asm volatile("s_waitcnt vmcnt(0)" ::: "memory");
  __builtin_amdgcn_s_barrier();

  const int l15 = lane & 15, lg = lane >> 4;
  const int swm = (l15 & 7) << 4;

  f32x4 acc[4];
#pragma unroll
  for (int mi = 0; mi < 4; ++mi) acc[mi] = (f32x4){0.f, 0.f, 0.f, 0.f};
#pragma unroll
  for (int ks = 0; ks < 6; ++ks) {
    const int col = (ks * 64 + lg * 16) ^ swm;
    const bf16x8 bv = *(const bf16x8*)(sBw + l15 * 384 + col);
#pragma unroll
    for (int mi = 0; mi < 4; ++mi) {
      const bf16x8 av = *(const bf16x8*)(sA + (mi * 16 + l15) * 384 + col);
      acc[mi] = __builtin_amdgcn_mfma_f32_16x16x32_bf16(av, bv, acc[mi], 0, 0, 0);
    }
  }
  // restage C into own (dead) sBw: [16 rows][136 B]
  asm volatile("s_waitcnt lgkmcnt(0)" ::: "memory");
#pragma unroll
  for (int mi = 0; mi < 4; ++mi) {
    u16x4 ov;
#pragma unroll
    for (int r = 0; r < 4; ++r) ov[r] = f2bf(acc[mi][r]);
    *(u16x4*)(sBw + l15 * 136 + mi * 32 + lg * 8) = ov;
  }
  asm volatile("s_waitcnt lgkmcnt(0)" ::: "memory");
  u16* Cb = C + (size_t)b * 576 * QS;
  const int jrow0 = j * 64 + wave * 16;
#pragma unroll
  for (int half = 0; half < 2; ++half) {
    const int row = half * 8 + (lane >> 3);
    const u16x8 val = *(const u16x8*)(sBw + row * 136 + (lane & 7) * 16);
    *(u16x8*)(Cb + (size_t)(jrow0 + row) * QS + m0 + (lane & 7) * 8) = val;
  }
}

// ---------------------------------------------------------------------------
// Final GEMM, same no-loop structure, fused v-transpose A-staging (v is
// QS-strided planar bf16 -> L2-set-rich). out[j][m] = sum_c v[m][c]*Weff[j][c],
// fp32 out. grid 3072 (j fastest of 3, XCD swizzle). LDS 48 KB, 3 blocks/CU.
__global__ __launch_bounds__(256, 3) void gemm_v_kernel(
    const u16* __restrict__ V, const u16* __restrict__ Weff,
    float* __restrict__ C, int nwg) {
  __shared__ __align__(16) char smem[49152];
  char* sA = smem;
  const int tid = threadIdx.x, wave = tid >> 6, lane = tid & 63;
  char* sBw = smem + 24576 + wave * 6144;

  const int p = blockIdx.x;
  const int id = (p & 7) * (nwg >> 3) + (p >> 3);
  const int j = id % 3;
  const int t = id / 3;
  const int m0 = (t & 255) * 64, b = t >> 8;

  const u16* Vb = V + (size_t)b * 576 * QS + m0;
  const char* Bb = (const char*)(Weff + (size_t)b * 192 * 192 +
                                 (size_t)(j * 64 + wave * 16) * 192);

  // A: global->reg (u16x8 per row, 4 rows per task)
  u16x8 vau[2][4];
#pragma unroll
  for (int pp = 0; pp < 2; ++pp) {
    const int task = pp * 256 + tid;  // 48 c-quads x 8 n-octs = 384 tasks
    if (task < 384) {
      const int cb = task >> 3, io = task & 7;
#pragma unroll
      for (int r = 0; r < 4; ++r)
        vau[pp][r] = *(const u16x8*)(Vb + (size_t)(cb * 4 + r) * QS + io * 8);
    }
  }
  // stage wave-private B
#pragma unroll
  for (int i = 0; i < 6; ++i) {
    const int d = i * 1024 + lane * 16;
    const int row = d / 384, inrow = d - row * 384;
    gload_lds16(Bb + row * 384 + (inrow ^ ((row & 7) << 4)), sBw + i * 1024);
  }
  // A: transpose + swizzled ds_write
#pragma unroll
  for (int pp = 0; pp < 2; ++pp) {
    const int task = pp * 256 + tid;
    if (task < 384) {
      const int cb = task >> 3, io = task & 7;
#pragma unroll
      for (int q = 0; q < 8; ++q) {
        const int n = io * 8 + q;
        u16x4 col;
        col[0] = vau[pp][0][q];
        col[1] = vau[pp][1][q];
        col[2] = vau[pp][2][q];
        col[3] = vau[pp][3][q];
        *(u16x4*)(sA + n * 384 + ((cb * 8) ^ ((n & 7) << 4))) = col;
      }
    }
  }
  asm volatile("s_waitcnt vmcnt(0) lgkmcnt(0)" ::: "memory");
  __builtin_amdgcn_s_barrier();

  const int l15 = lane & 15, lg = lane >> 4;
  const int swm = (l15 & 7) << 4;

  f32x4 acc[4];
#pragma unroll
  for (int mi = 0; mi < 4; ++mi) acc[mi] = (f32x4){0.f, 0.f, 0.f, 0.f};
#pragma unroll
  for (int ks = 0; ks < 6; ++ks) {
    const int col = (ks * 64 + lg * 16) ^ swm;
    const bf16x8 bv = *(const bf16x8*)(sBw + l15 * 384 + col);
#pragma unroll
    for (int mi = 0; mi < 4; ++mi) {
      const bf16x8 av = *(const bf16x8*)(sA + (mi * 16 + l15) * 384 + col);
      acc[mi] = __builtin_amdgcn_mfma_f32_16x16x32_bf16(av, bv, acc[mi], 0, 0, 0);
    }
  }
  // restage f32 C into own sBw: [16 rows][272 B]
  asm volatile("s_waitcnt lgkmcnt(0)" ::: "memory");
#pragma unroll
  for (int mi = 0; mi < 4; ++mi)
    *(f32x4*)(sBw + l15 * 272 + mi * 64 + lg * 16) = acc[mi];
  asm volatile("s_waitcnt lgkmcnt(0)" ::: "memory");
  float* Cb = C + (size_t)b * 192 * 16384;
  const int jrow0 = j * 64 + wave * 16;
#pragma unroll
  for (int q = 0; q < 4; ++q) {
    const int row = q * 4 + (lane >> 4);
    const f32x4 val = *(const f32x4*)(sBw + row * 272 + (lane & 15) * 16);
    *(f32x4*)(Cb + (size_t)(jrow0 + row) * 16384 + m0 + (lane & 15) * 4) = val;
  }
}

// ---------------------------------------------------------------------------
// Depthwise 3x3 (pad 1), in-place on bf16 [b][576][QS-strided 128x128];
// per-channel sum-of-squares. One block per (b, channel).
__global__ __launch_bounds__(256) void dwconv_kernel(
    u16* __restrict__ qkv, const float* __restrict__ wdw,
    float* __restrict__ sq) {
  __shared__ u16 img[16384];
  __shared__ float red[4];
  const int o = blockIdx.x, b = blockIdx.y;
  const size_t base = ((size_t)b * 576 + o) * QS;
  const int tid = threadIdx.x, wave = tid >> 6, lane = tid & 63;
#pragma unroll
  for (int i = 0; i < 8; ++i) {
    const int off = (i * 4 + wave) * 1024;
    gload_lds16((const char*)qkv + base * 2 + off + lane * 16, (char*)img + off);
  }
  asm volatile("s_waitcnt vmcnt(0)" ::: "memory");
  __syncthreads();
  float w[9];
#pragma unroll
  for (int j = 0; j < 9; ++j) w[j] = wdw[o * 9 + j];
  float sqacc = 0.f;
  for (int it = 0; it < 8; ++it) {
    const int chunk = it * 256 + tid;
    const int px0 = chunk * 8;
    const int y = px0 >> 7, x0 = px0 & 127;
    float acc[8];
#pragma unroll
    for (int j = 0; j < 8; ++j) acc[j] = 0.f;
#pragma unroll
    for (int dy = -1; dy <= 1; ++dy) {
      const int yy = y + dy;
      float v[10];
      if (yy >= 0 && yy <= 127) {
        const u16* rowp = img + yy * 128 + x0;
        u16x8 m = *(const u16x8*)rowp;
#pragma unroll
        for (int j = 0; j < 8; ++j) v[j + 1] = bf2f(m[j]);
        v[0] = (x0 > 0) ? bf2f(rowp[-1]) : 0.f;
        v[9] = (x0 < 120) ? bf2f(rowp[8]) : 0.f;
      } else {
#pragma unroll
        for (int j = 0; j < 10; ++j) v[j] = 0.f;
      }
      const float w0 = w[(dy + 1) * 3], w1 = w[(dy + 1) * 3 + 1],
                  w2 = w[(dy + 1) * 3 + 2];
#pragma unroll
      for (int j = 0; j < 8; ++j) acc[j] += w0 * v[j] + w1 * v[j + 1] + w2 * v[j + 2];
    }
    u16x8 ov;
#pragma unroll
    for (int j = 0; j < 8; ++j) {
      sqacc += acc[j] * acc[j];
      ov[j] = f2bf(acc[j]);
    }
    *(u16x8*)(qkv + base + px0) = ov;
  }
#pragma unroll
  for (int s = 32; s > 0; s >>= 1) sqacc += __shfl_xor(sqacc, s, 64);
  if (lane == 0) red[wave] = sqacc;
  __syncthreads();
  if (tid == 0) sq[b * 576 + o] = red[0] + red[1] + red[2] + red[3];
}

// ---------------------------------------------------------------------------
// Gram partials over 512-n blocks (4 waves x 128 n), swizzled tiles.
__global__ __launch_bounds__(256) void gram_kernel(
    const u16* __restrict__ qkv, float* __restrict__ partial) {
  __shared__ u16 tiles[4 * 3072];
  __shared__ float red[4 * 2304];
  const int bh = blockIdx.y, b = bh >> 2, h = bh & 3;
  const int g = blockIdx.x;
  const int wave = threadIdx.x >> 6, lane = threadIdx.x & 63;
  const int n0 = g * 512 + wave * 128;
  const u16* qb = qkv + ((size_t)b * 576 + h * 48) * QS;
  const u16* kb = qb + (size_t)192 * QS;
  char* tl = (char*)(tiles + wave * 3072);
  const int l15 = lane & 15, lg = lane >> 4;
  const int swz = (l15 & 3) << 4;
  f32x4 acc[3][3];
#pragma unroll
  for (int i = 0; i < 3; ++i)
#pragma unroll
    for (int j = 0; j < 3; ++j) acc[i][j] = (f32x4){0.f, 0.f, 0.f, 0.f};

  for (int ks = 0; ks < 4; ++ks) {
    const int nn = n0 + ks * 32;
    asm volatile("s_waitcnt lgkmcnt(0)" ::: "memory");
#pragma unroll
    for (int i = 0; i < 6; ++i) {
      const int flat = i * 1024 + lane * 16;
      const int row = flat >> 6, colb = flat & 63;
      const u16* src = (row < 48) ? (qb + (size_t)row * QS + nn)
                                  : (kb + (size_t)(row - 48) * QS + nn);
      gload_lds16((const char*)src + (colb ^ ((row & 3) << 4)), tl + i * 1024);
    }
    asm volatile("s_waitcnt vmcnt(0)" ::: "memory");
    bf16x8 qf[3], kf[3];
#pragma unroll
    for (int f = 0; f < 3; ++f) {
      qf[f] = *(const bf16x8*)(tl + (f * 16 + l15) * 64 + ((lg * 16) ^ swz));
      kf[f] = *(const bf16x8*)(tl + (48 + f * 16 + l15) * 64 + ((lg * 16) ^ swz));
    }
#pragma unroll
    for (int i = 0; i < 3; ++i)
#pragma unroll
      for (int j = 0; j < 3; ++j)
        acc[i][j] = __builtin_amdgcn_mfma_f32_16x16x32_bf16(qf[i], kf[j],
                                                            acc[i][j], 0, 0, 0);
  }
  {
    float* rw = red + wave * 2304;
#pragma unroll
    for (int i = 0; i < 3; ++i)
#pragma unroll
      for (int j = 0; j < 3; ++j)
#pragma unroll
        for (int r = 0; r < 4; ++r)
          rw[(i * 16 + lg * 4 + r) * 48 + (j * 16 + l15)] = acc[i][j][r];
  }
  __syncthreads();
#pragma unroll
  for (int it = 0; it < 9; ++it) {
    const int p = it * 256 + threadIdx.x;
    const float s = red[p] + red[2304 + p] + red[4608 + p] + red[6912 + p];
    partial[((size_t)bh * 2304 + p) * 32 + g] = s;
  }
}

// ---------------------------------------------------------------------------
__global__ __launch_bounds__(256) void reduce_partial_kernel(
    const float* __restrict__ partial, float* __restrict__ G) {
  const int idx = blockIdx.x * 256 + threadIdx.x;
  const f32x4* pp = (const f32x4*)(partial + (size_t)idx * 32);
  const f32x4 a = (pp[0] + pp[1]) + (pp[2] + pp[3]) +
                  (pp[4] + pp[5]) + (pp[6] + pp[7]);
  G[idx] = a.x + a.y + a.z + a.w;
}

// ---------------------------------------------------------------------------
// Normalize, softmax, fold attn into projection (row-major Weff out).
__global__ __launch_bounds__(256) void softmax_weff_kernel(
    const float* __restrict__ Gin, const float* __restrict__ sq,
    const float* __restrict__ temp, const float* __restrict__ wproj,
    u16* __restrict__ weff) {
  __shared__ float G[2304];
  __shared__ float wp[192 * 49];
  __shared__ float nq[48], nk[48];
  const int bh = blockIdx.x, b = bh >> 2, h = bh & 3;
  const int tid = threadIdx.x;
#pragma unroll
  for (int it = 0; it < 36; ++it) {
    const int j = it * 256 + tid;
    const int o = j / 48, c = j - o * 48;
    wp[o * 49 + c] = wproj[o * 192 + h * 48 + c];
  }
#pragma unroll
  for (int it = 0; it < 9; ++it) {
    const int p = it * 256 + tid;
    G[p] = Gin[(size_t)bh * 2304 + p];
  }
  if (tid < 48) {
    nq[tid] = fmaxf(sqrtf(sq[b * 576 + h * 48 + tid]), 1e-12f);
    nk[tid] = fmaxf(sqrtf(sq[b * 576 + 192 + h * 48 + tid]), 1e-12f);
  }
  __syncthreads();
  if (tid < 48) {
    const int r = tid;
    const float inq = temp[h] / nq[r];
    float L[48];
    float mx = -3.4e38f;
#pragma unroll 4
    for (int d = 0; d < 48; ++d) {
      const float v = G[r * 48 + d] * inq / nk[d];
      L[d] = v;
      mx = fmaxf(mx, v);
    }
    float s = 0.f;
#pragma unroll 4
    for (int d = 0; d < 48; ++d) {
      const float e = __expf(L[d] - mx);
      L[d] = e;
      s += e;
    }
    const float inv = 1.f / s;
#pragma unroll 4
    for (int d = 0; d < 48; ++d) G[r * 48 + d] = L[d] * inv;
  }
  __syncthreads();
  if (tid < 192) {
    const int o = tid;
    f32x4 acc[12];
#pragma unroll
    for (int dv = 0; dv < 12; ++dv) acc[dv] = (f32x4){0.f, 0.f, 0.f, 0.f};
    for (int c = 0; c < 48; ++c) {
      const float w = wp[o * 49 + c];
      const f32x4* at = (const f32x4*)(G + c * 48);
#pragma unroll
      for (int dv = 0; dv < 12; ++dv) acc[dv] += w * at[dv];
    }
    u16* op = weff + ((size_t)b * 192 + o) * 192 + h * 48;
#pragma unroll
    for (int g8 = 0; g8 < 6; ++g8) {
      u16x8 ov;
#pragma unroll
      for (int j = 0; j < 8; ++j) {
        const int d = g8 * 8 + j;
        ov[j] = f2bf(acc[d >> 2][d & 3]);
      }
      *(u16x8*)(op + g8 * 8) = ov;
    }
  }
}

// ---------------------------------------------------------------------------
extern "C" void kernel_launch(void* const* d_in, const int* in_sizes, int n_in,
                              void* d_out, int out_size, void* d_ws,
                              size_t ws_size, hipStream_t stream) {
  (void)in_sizes; (void)n_in; (void)out_size; (void)ws_size;
  const float* x      = (const float*)d_in[0];  // [4][192][128][128]
  const float* w_qkv  = (const float*)d_in[1];  // [576][192]
  const float* w_dw   = (const float*)d_in[2];  // [576][9]
  const float* w_proj = (const float*)d_in[3];  // [192][192]
  const float* temp   = (const float*)d_in[4];  // [4]

  char* ws = (char*)d_ws;
  u16*   qkv     = (u16*)ws;                    // 4*576*QS*2 = 75,792,384 B
  float* partial = (float*)(ws + 75792384);     //  4,718,592 B [16][2304][32]
  float* G       = (float*)(ws + 80510976);     //    147,456 B
  float* sq      = (float*)(ws + 80658432);     //      9,216 B
  u16*   Wq      = (u16*)(ws + 80667648);       //    221,184 B [576][192]
  u16*   Weff    = (u16*)(ws + 80888832);       //    294,912 B [4][192][192]
  u16*   Xt      = (u16*)d_out;                 // 25.2 MB scratch (dead before final)

  // w_qkv -> bf16
  convert_w_kernel<<<dim3(432), 256, 0, stream>>>(w_qkv, Wq, 110592);
  // x -> Xt [b][n][192] bf16 (L2-set-rich 384 B stride)
  transpose_f32_kernel<<<dim3(256, 3, 4), 256, 0, stream>>>(x, Xt);
  // qkv = Xt @ Wq^T  (no-loop small blocks, XCD-swizzled)
  gemm_xt_kernel<<<dim3(9216), 256, 0, stream>>>(Xt, Wq, qkv, 9216);
  // depthwise 3x3 in-place + per-channel sum-of-squares
  dwconv_kernel<<<dim3(576, 4), 256, 0, stream>>>(qkv, w_dw, sq);
  // gram partials
  gram_kernel<<<dim3(32, 16), 256, 0, stream>>>(qkv, partial);
  // wide cross-chunk reduction
  reduce_partial_kernel<<<dim3(144), 256, 0, stream>>>(partial, G);
  // normalize + softmax + fold into projection
  softmax_weff_kernel<<<dim3(16), 256, 0, stream>>>(G, sq, temp, w_proj, Weff);
  // out = v @ Weff^T  (fused v-transpose, no-loop small blocks)
  gemm_v_kernel<<<dim3(3072), 256, 0, stream>>>(qkv + (size_t)384 * QS, Weff,
                                                (float*)d_out, 3072);
}

// Round 13
// 146.635 us; speedup vs baseline: 1.0536x; 1.0536x over previous
//
#include <hip/hip_runtime.h>

typedef unsigned short u16;
typedef float f32x4 __attribute__((ext_vector_type(4)));
typedef __bf16 bf16x8 __attribute__((ext_vector_type(8)));
typedef unsigned short u16x8 __attribute__((ext_vector_type(8)));
typedef unsigned short u16x4 __attribute__((ext_vector_type(4)));

#define DEV static __device__ __forceinline__

// padded row stride for the qkv intermediate (breaks pow-2 L2-set/channel camping)
#define QS 16448

DEV u16 f2bf(float f) {
  unsigned int u = __float_as_uint(f);
  u += 0x7FFFu + ((u >> 16) & 1u);   // round-to-nearest-even
  return (u16)(u >> 16);
}
DEV float bf2f(u16 h) { return __uint_as_float(((unsigned int)h) << 16); }

// async global->LDS, 16B per lane. LDS dest = wave-uniform base + lane*16.
DEV void gload_lds16(const void* g, void* l) {
  __builtin_amdgcn_global_load_lds(
      (__attribute__((address_space(1))) void*)(unsigned long long)g,
      (__attribute__((address_space(3))) void*)l, 16, 0, 0);
}

// counted vmcnt wait; n is compile-time constant after full unroll
DEV void vm_wait(int n) {
  switch (n) {
    case 0:  asm volatile("s_waitcnt vmcnt(0)" ::: "memory"); break;
    case 1:  asm volatile("s_waitcnt vmcnt(1)" ::: "memory"); break;
    case 2:  asm volatile("s_waitcnt vmcnt(2)" ::: "memory"); break;
    case 6:  asm volatile("s_waitcnt vmcnt(6)" ::: "memory"); break;
    case 7:  asm volatile("s_waitcnt vmcnt(7)" ::: "memory"); break;
    case 8:  asm volatile("s_waitcnt vmcnt(8)" ::: "memory"); break;
    default: asm volatile("s_waitcnt vmcnt(14)" ::: "memory"); break;
  }
}

// ---------------------------------------------------------------------------
// K0b: convert w_qkv fp32 -> bf16 (plain row-major [576][192])
__global__ __launch_bounds__(256) void convert_w_kernel(
    const float* __restrict__ in, u16* __restrict__ out, int n) {
  int i = blockIdx.x * 256 + threadIdx.x;
  if (i < n) out[i] = f2bf(in[i]);
}

// ---------------------------------------------------------------------------
// B^T GEMM, wave-autonomous, SMALL BLOCKS (BM=32) for latency amortization.
// C[j][m] = sum_k A^T[m][k]*B[j][k], K=192. 4 waves; wave w owns NJT 16-ch
// B-tiles (wave-private 2x6 KB double buffer, counted wave-local vmcnt, no
// block-wide sync after the single A barrier). A (32 px x 192 ch, 12 KB)
// staged via fused transpose+convert at XOR-swizzled addresses; after the
// af-hoist sA is reused as per-wave restage buffers so stores are 64/128-B
// segments. LDS 60 KB -> 2 blocks/CU; grid 2048 blocks (2x R11) halves the
// serial block rounds that dominated.
template <bool IN_F32, bool OUT_BF16, int NJT>
__global__ __launch_bounds__(256, 2) void gemm_bt_kernel(
    const void* __restrict__ Av, const u16* __restrict__ B,
    void* __restrict__ Cv, size_t aBatch, int aStride, size_t bBatch,
    size_t cBatch, int ldC) {
  __shared__ __align__(16) char smem[61440];
  char* sA = smem;  // [32][384B] content-swizzled; later: restage buffers

  const int tid = threadIdx.x, wave = tid >> 6, lane = tid & 63;
  const int m0 = blockIdx.x * 32, b = blockIdx.y;
  const char* Bbase = (const char*)(B + (size_t)b * bBatch);
  char* bufs = smem + 12288 + wave * 12288;  // wave-private 2 x 6144 B
  const int jwbase = wave * (NJT * 16);
  constexpr int S = OUT_BF16 ? 1 : 2;  // store instrs per tile

  // ---- A: issue global loads first (B-stage gloads go behind them)
  f32x4 vaf[2][4];
  u16x8 vau[4];
  if (IN_F32) {
    const float* Xb = (const float*)Av + (size_t)b * aBatch + m0;
#pragma unroll
    for (int p = 0; p < 2; ++p) {
      const int task = p * 256 + tid;  // 48 c-quads x 8 px-quads = 384
      if (task < 384) {
        const int cb = task >> 3, io = task & 7;
#pragma unroll
        for (int r = 0; r < 4; ++r)
          vaf[p][r] = *(const f32x4*)(Xb + (size_t)(cb * 4 + r) * aStride +
                                      io * 4);
      }
    }
  } else {
    const u16* Vb = (const u16*)Av + (size_t)b * aBatch + m0;
    if (tid < 192) {  // 48 c-quads x 4 px-octs
      const int cb = tid >> 2, io = tid & 3;
#pragma unroll
      for (int r = 0; r < 4; ++r)
        vau[r] = *(const u16x8*)(Vb + (size_t)(cb * 4 + r) * aStride + io * 8);
    }
  }
  // ---- stage wave-private B tiles 0 and 1
#pragma unroll
  for (int t = 0; t < 2; ++t) {
    if (t < NJT) {
#pragma unroll
      for (int i = 0; i < 6; ++i) {
        const int d = i * 1024 + lane * 16;
        const int row = d / 384, inrow = d - row * 384;
        gload_lds16(Bbase + (size_t)(jwbase + t * 16 + row) * 384 +
                        (inrow ^ ((row & 7) << 4)),
                    bufs + t * 6144 + i * 1024);
      }
    }
  }
  // ---- A: transpose + convert + swizzled ds_write
  if (IN_F32) {
#pragma unroll
    for (int p = 0; p < 2; ++p) {
      const int task = p * 256 + tid;
      if (task < 384) {
        const int cb = task >> 3, io = task & 7;
#pragma unroll
        for (int j = 0; j < 4; ++j) {
          const int n = io * 4 + j;
          u16x4 col;
          col[0] = f2bf(vaf[p][0][j]);
          col[1] = f2bf(vaf[p][1][j]);
          col[2] = f2bf(vaf[p][2][j]);
          col[3] = f2bf(vaf[p][3][j]);
          *(u16x4*)(sA + n * 384 + ((cb * 8) ^ ((n & 7) << 4))) = col;
        }
      }
    }
  } else {
    if (tid < 192) {
      const int cb = tid >> 2, io = tid & 3;
#pragma unroll
      for (int j = 0; j < 8; ++j) {
        const int n = io * 8 + j;
        u16x4 col;
        col[0] = vau[0][j];
        col[1] = vau[1][j];
        col[2] = vau[2][j];
        col[3] = vau[3][j];
        *(u16x4*)(sA + n * 384 + ((cb * 8) ^ ((n & 7) << 4))) = col;
      }
    }
  }
  asm volatile("s_waitcnt lgkmcnt(0)" ::: "memory");
  __builtin_amdgcn_s_barrier();  // sA staged

  const int l15 = lane & 15, lg = lane >> 4;
  const int swm = (l15 & 7) << 4;

  // ---- A fragments hoisted (32 px x 192 ch per wave); sA dead after
  bf16x8 af[2][6];
#pragma unroll
  for (int mi = 0; mi < 2; ++mi)
#pragma unroll
    for (int ks = 0; ks < 6; ++ks)
      af[mi][ks] = *(const bf16x8*)(sA + (mi * 16 + l15) * 384 +
                                    ((ks * 64 + lg * 16) ^ swm));
  asm volatile("s_waitcnt lgkmcnt(0)" ::: "memory");
  __builtin_amdgcn_s_barrier();  // all waves done reading sA -> reusable

  char* rbuf = sA + wave * 3072;  // wave-private restage buffer

  // ---- wave-private tile loop: no barriers, counted wave-local vmcnt
#pragma unroll
  for (int t = 0; t < NJT; ++t) {
    // stage(t) must be done; stores(t-1)[S] + stage(t+1)[6] stay in flight
    vm_wait(t == 0 ? (NJT > 1 ? 6 : 0) : (S + (t + 1 < NJT ? 6 : 0)));
    __builtin_amdgcn_sched_barrier(0);
    char* bw = bufs + (t & 1) * 6144;
    bf16x8 bfv[6];
#pragma unroll
    for (int ks = 0; ks < 6; ++ks)
      bfv[ks] = *(const bf16x8*)(bw + l15 * 384 + ((ks * 64 + lg * 16) ^ swm));
    f32x4 acc[2];
#pragma unroll
    for (int mi = 0; mi < 2; ++mi) acc[mi] = (f32x4){0.f, 0.f, 0.f, 0.f};
#pragma unroll
    for (int ks = 0; ks < 6; ++ks)
#pragma unroll
      for (int mi = 0; mi < 2; ++mi)
        acc[mi] = __builtin_amdgcn_mfma_f32_16x16x32_bf16(af[mi][ks], bfv[ks],
                                                          acc[mi], 0, 0, 0);
    // ---- restaged, coalesced store of tile t (16 j-rows x 32 px)
    const int jrow0 = jwbase + t * 16;
    if (OUT_BF16) {
      // restage [16 j][72 B] (64 B data + 8 pad)
#pragma unroll
      for (int mi = 0; mi < 2; ++mi) {
        u16x4 ov;
#pragma unroll
        for (int r = 0; r < 4; ++r) ov[r] = f2bf(acc[mi][r]);
        *(u16x4*)(rbuf + l15 * 72 + mi * 32 + lg * 8) = ov;
      }
      asm volatile("s_waitcnt lgkmcnt(0)" ::: "memory");
      u16* Cb = (u16*)Cv + (size_t)b * cBatch;
      {  // 1 instr: 16 rows x 64 B
        const int row = lane >> 2;
        const u16x8 val = *(const u16x8*)(rbuf + row * 72 + (lane & 3) * 16);
        *(u16x8*)(Cb + (size_t)(jrow0 + row) * ldC + m0 + (lane & 3) * 8) = val;
      }
    } else {
      // restage f32 [16 j][144 B] (128 B data + 16 pad)
#pragma unroll
      for (int mi = 0; mi < 2; ++mi)
        *(f32x4*)(rbuf + l15 * 144 + mi * 64 + lg * 16) = acc[mi];
      asm volatile("s_waitcnt lgkmcnt(0)" ::: "memory");
      float* Cb = (float*)Cv + (size_t)b * cBatch;
#pragma unroll
      for (int q = 0; q < 2; ++q) {  // 2 instrs x 8 rows x 128 B
        const int row = q * 8 + (lane >> 3);
        const f32x4 val = *(const f32x4*)(rbuf + row * 144 + (lane & 7) * 16);
        *(f32x4*)(Cb + (size_t)(jrow0 + row) * ldC + m0 + (lane & 7) * 4) = val;
      }
    }
    // prefetch tile t+2 into the buffer drained this iteration
    if (t + 2 < NJT) {
      __builtin_amdgcn_sched_barrier(0);
#pragma unroll
      for (int i = 0; i < 6; ++i) {
        const int d = i * 1024 + lane * 16;
        const int row = d / 384, inrow = d - row * 384;
        gload_lds16(Bbase + (size_t)(jwbase + (t + 2) * 16 + row) * 384 +
                        (inrow ^ ((row & 7) << 4)),
                    bw + i * 1024);
      }
    }
  }
}

// ---------------------------------------------------------------------------
// Depthwise 3x3 (pad 1), in-place on bf16 [b][576][QS-strided 128x128];
// per-channel sum-of-squares. One block per (b, channel).
__global__ __launch_bounds__(256) void dwconv_kernel(
    u16* __restrict__ qkv, const float* __restrict__ wdw,
    float* __restrict__ sq) {
  __shared__ u16 img[16384];
  __shared__ float red[4];
  const int o = blockIdx.x, b = blockIdx.y;
  const size_t base = ((size_t)b * 576 + o) * QS;
  const int tid = threadIdx.x, wave = tid >> 6, lane = tid & 63;
#pragma unroll
  for (int i = 0; i < 8; ++i) {
    const int off = (i * 4 + wave) * 1024;
    gload_lds16((const char*)qkv + base * 2 + off + lane * 16, (char*)img + off);
  }
  asm volatile("s_waitcnt vmcnt(0)" ::: "memory");
  __syncthreads();
  float w[9];
#pragma unroll
  for (int j = 0; j < 9; ++j) w[j] = wdw[o * 9 + j];
  float sqacc = 0.f;
  for (int it = 0; it < 8; ++it) {
    const int chunk = it * 256 + tid;
    const int px0 = chunk * 8;
    const int y = px0 >> 7, x0 = px0 & 127;
    float acc[8];
#pragma unroll
    for (int j = 0; j < 8; ++j) acc[j] = 0.f;
#pragma unroll
    for (int dy = -1; dy <= 1; ++dy) {
      const int yy = y + dy;
      float v[10];
      if (yy >= 0 && yy <= 127) {
        const u16* rowp = img + yy * 128 + x0;
        u16x8 m = *(const u16x8*)rowp;
#pragma unroll
        for (int j = 0; j < 8; ++j) v[j + 1] = bf2f(m[j]);
        v[0] = (x0 > 0) ? bf2f(rowp[-1]) : 0.f;
        v[9] = (x0 < 120) ? bf2f(rowp[8]) : 0.f;
      } else {
#pragma unroll
        for (int j = 0; j < 10; ++j) v[j] = 0.f;
      }
      const float w0 = w[(dy + 1) * 3], w1 = w[(dy + 1) * 3 + 1],
                  w2 = w[(dy + 1) * 3 + 2];
#pragma unroll
      for (int j = 0; j < 8; ++j) acc[j] += w0 * v[j] + w1 * v[j + 1] + w2 * v[j + 2];
    }
    u16x8 ov;
#pragma unroll
    for (int j = 0; j < 8; ++j) {
      sqacc += acc[j] * acc[j];
      ov[j] = f2bf(acc[j]);
    }
    *(u16x8*)(qkv + base + px0) = ov;
  }
#pragma unroll
  for (int s = 32; s > 0; s >>= 1) sqacc += __shfl_xor(sqacc, s, 64);
  if (lane == 0) red[wave] = sqacc;
  __syncthreads();
  if (tid == 0) sq[b * 576 + o] = red[0] + red[1] + red[2] + red[3];
}

// ---------------------------------------------------------------------------
// Gram partials over 512-n blocks (4 waves x 128 n), swizzled tiles.
__global__ __launch_bounds__(256) void gram_kernel(
    const u16* __restrict__ qkv, float* __restrict__ partial) {
  __shared__ u16 tiles[4 * 3072];
  __shared__ float red[4 * 2304];
  const int bh = blockIdx.y, b = bh >> 2, h = bh & 3;
  const int g = blockIdx.x;
  const int wave = threadIdx.x >> 6, lane = threadIdx.x & 63;
  const int n0 = g * 512 + wave * 128;
  const u16* qb = qkv + ((size_t)b * 576 + h * 48) * QS;
  const u16* kb = qb + (size_t)192 * QS;
  char* tl = (char*)(tiles + wave * 3072);
  const int l15 = lane & 15, lg = lane >> 4;
  const int swz = (l15 & 3) << 4;
  f32x4 acc[3][3];
#pragma unroll
  for (int i = 0; i < 3; ++i)
#pragma unroll
    for (int j = 0; j < 3; ++j) acc[i][j] = (f32x4){0.f, 0.f, 0.f, 0.f};

  for (int ks = 0; ks < 4; ++ks) {
    const int nn = n0 + ks * 32;
    asm volatile("s_waitcnt lgkmcnt(0)" ::: "memory");
#pragma unroll
    for (int i = 0; i < 6; ++i) {
      const int flat = i * 1024 + lane * 16;
      const int row = flat >> 6, colb = flat & 63;
      const u16* src = (row < 48) ? (qb + (size_t)row * QS + nn)
                                  : (kb + (size_t)(row - 48) * QS + nn);
      gload_lds16((const char*)src + (colb ^ ((row & 3) << 4)), tl + i * 1024);
    }
    asm volatile("s_waitcnt vmcnt(0)" ::: "memory");
    bf16x8 qf[3], kf[3];
#pragma unroll
    for (int f = 0; f < 3; ++f) {
      qf[f] = *(const bf16x8*)(tl + (f * 16 + l15) * 64 + ((lg * 16) ^ swz));
      kf[f] = *(const bf16x8*)(tl + (48 + f * 16 + l15) * 64 + ((lg * 16) ^ swz));
    }
#pragma unroll
    for (int i = 0; i < 3; ++i)
#pragma unroll
      for (int j = 0; j < 3; ++j)
        acc[i][j] = __builtin_amdgcn_mfma_f32_16x16x32_bf16(qf[i], kf[j],
                                                            acc[i][j], 0, 0, 0);
  }
  {
    float* rw = red + wave * 2304;
#pragma unroll
    for (int i = 0; i < 3; ++i)
#pragma unroll
      for (int j = 0; j < 3; ++j)
#pragma unroll
        for (int r = 0; r < 4; ++r)
          rw[(i * 16 + lg * 4 + r) * 48 + (j * 16 + l15)] = acc[i][j][r];
  }
  __syncthreads();
#pragma unroll
  for (int it = 0; it < 9; ++it) {
    const int p = it * 256 + threadIdx.x;
    const float s = red[p] + red[2304 + p] + red[4608 + p] + red[6912 + p];
    partial[((size_t)bh * 2304 + p) * 32 + g] = s;
  }
}

// ---------------------------------------------------------------------------
__global__ __launch_bounds__(256) void reduce_partial_kernel(
    const float* __restrict__ partial, float* __restrict__ G) {
  const int idx = blockIdx.x * 256 + threadIdx.x;
  const f32x4* pp = (const f32x4*)(partial + (size_t)idx * 32);
  const f32x4 a = (pp[0] + pp[1]) + (pp[2] + pp[3]) +
                  (pp[4] + pp[5]) + (pp[6] + pp[7]);
  G[idx] = a.x + a.y + a.z + a.w;
}

// ---------------------------------------------------------------------------
// Normalize, softmax, fold attn into projection (row-major Weff out).
__global__ __launch_bounds__(256) void softmax_weff_kernel(
    const float* __restrict__ Gin, const float* __restrict__ sq,
    const float* __restrict__ temp, const float* __restrict__ wproj,
    u16* __restrict__ weff) {
  __shared__ float G[2304];
  __shared__ float wp[192 * 49];
  __shared__ float nq[48], nk[48];
  const int bh = blockIdx.x, b = bh >> 2, h = bh & 3;
  const int tid = threadIdx.x;
#pragma unroll
  for (int it = 0; it < 36; ++it) {
    const int j = it * 256 + tid;
    const int o = j / 48, c = j - o * 48;
    wp[o * 49 + c] = wproj[o * 192 + h * 48 + c];
  }
#pragma unroll
  for (int it = 0; it < 9; ++it) {
    const int p = it * 256 + tid;
    G[p] = Gin[(size_t)bh * 2304 + p];
  }
  if (tid < 48) {
    nq[tid] = fmaxf(sqrtf(sq[b * 576 + h * 48 + tid]), 1e-12f);
    nk[tid] = fmaxf(sqrtf(sq[b * 576 + 192 + h * 48 + tid]), 1e-12f);
  }
  __syncthreads();
  if (tid < 48) {
    const int r = tid;
    const float inq = temp[h] / nq[r];
    float L[48];
    float mx = -3.4e38f;
#pragma unroll 4
    for (int d = 0; d < 48; ++d) {
      const float v = G[r * 48 + d] * inq / nk[d];
      L[d] = v;
      mx = fmaxf(mx, v);
    }
    float s = 0.f;
#pragma unroll 4
    for (int d = 0; d < 48; ++d) {
      const float e = __expf(L[d] - mx);
      L[d] = e;
      s += e;
    }
    const float inv = 1.f / s;
#pragma unroll 4
    for (int d = 0; d < 48; ++d) G[r * 48 + d] = L[d] * inv;
  }
  __syncthreads();
  if (tid < 192) {
    const int o = tid;
    f32x4 acc[12];
#pragma unroll
    for (int dv = 0; dv < 12; ++dv) acc[dv] = (f32x4){0.f, 0.f, 0.f, 0.f};
    for (int c = 0; c < 48; ++c) {
      const float w = wp[o * 49 + c];
      const f32x4* at = (const f32x4*)(G + c * 48);
#pragma unroll
      for (int dv = 0; dv < 12; ++dv) acc[dv] += w * at[dv];
    }
    u16* op = weff + ((size_t)b * 192 + o) * 192 + h * 48;
#pragma unroll
    for (int g8 = 0; g8 < 6; ++g8) {
      u16x8 ov;
#pragma unroll
      for (int j = 0; j < 8; ++j) {
        const int d = g8 * 8 + j;
        ov[j] = f2bf(acc[d >> 2][d & 3]);
      }
      *(u16x8*)(op + g8 * 8) = ov;
    }
  }
}

// ---------------------------------------------------------------------------
extern "C" void kernel_launch(void* const* d_in, const int* in_sizes, int n_in,
                              void* d_out, int out_size, void* d_ws,
                              size_t ws_size, hipStream_t stream) {
  (void)in_sizes; (void)n_in; (void)out_size; (void)ws_size;
  const float* x      = (const float*)d_in[0];  // [4][192][128][128]
  const float* w_qkv  = (const float*)d_in[1];  // [576][192]
  const float* w_dw   = (const float*)d_in[2];  // [576][9]
  const float* w_proj = (const float*)d_in[3];  // [192][192]
  const float* temp   = (const float*)d_in[4];  // [4]

  char* ws = (char*)d_ws;
  u16*   qkv     = (u16*)ws;                    // 4*576*QS*2 = 75,792,384 B
  float* partial = (float*)(ws + 75792384);     //  4,718,592 B [16][2304][32]
  float* G       = (float*)(ws + 80510976);     //    147,456 B
  float* sq      = (float*)(ws + 80658432);     //      9,216 B
  u16*   Wq      = (u16*)(ws + 80667648);       //    221,184 B [576][192]
  u16*   Weff    = (u16*)(ws + 80888832);       //    294,912 B [4][192][192]

  // w_qkv -> bf16
  convert_w_kernel<<<dim3(432), 256, 0, stream>>>(w_qkv, Wq, 110592);
  // qkv[b][o][n] = sum_c x[c][n]*Wq[o][c]  (fused x-transpose; 9 tiles/wave)
  gemm_bt_kernel<true, true, 9><<<dim3(512, 4), 256, 0, stream>>>(
      x, Wq, qkv, (size_t)192 * 16384, 16384, 0, (size_t)576 * QS, QS);
  // depthwise 3x3 in-place + per-channel sum-of-squares
  dwconv_kernel<<<dim3(576, 4), 256, 0, stream>>>(qkv, w_dw, sq);
  // gram partials
  gram_kernel<<<dim3(32, 16), 256, 0, stream>>>(qkv, partial);
  // wide cross-chunk reduction
  reduce_partial_kernel<<<dim3(144), 256, 0, stream>>>(partial, G);
  // normalize + softmax + fold into projection
  softmax_weff_kernel<<<dim3(16), 256, 0, stream>>>(G, sq, temp, w_proj, Weff);
  // out[b][o][n] = sum_c v[c][n]*Weff[o][c]  (fused v-transpose; 3 tiles/wave)
  gemm_bt_kernel<false, false, 3><<<dim3(512, 4), 256, 0, stream>>>(
      qkv + (size_t)384 * QS, Weff, d_out, (size_t)576 * QS, QS,
      (size_t)192 * 192, (size_t)192 * 16384, 16384);
}

// Round 14
// 136.796 us; speedup vs baseline: 1.1294x; 1.0719x over previous
//
#include <hip/hip_runtime.h>

typedef unsigned short u16;
typedef float f32x4 __attribute__((ext_vector_type(4)));
typedef __bf16 bf16x8 __attribute__((ext_vector_type(8)));
typedef unsigned short u16x8 __attribute__((ext_vector_type(8)));
typedef unsigned short u16x4 __attribute__((ext_vector_type(4)));

#define DEV static __device__ __forceinline__

DEV u16 f2bf(float f) {
  unsigned int u = __float_as_uint(f);
  u += 0x7FFFu + ((u >> 16) & 1u);   // round-to-nearest-even
  return (u16)(u >> 16);
}
DEV float bf2f(u16 h) { return __uint_as_float(((unsigned int)h) << 16); }

// async global->LDS, 16B per lane. LDS dest = wave-uniform base + lane*16.
DEV void gload_lds16(const void* g, void* l) {
  __builtin_amdgcn_global_load_lds(
      (__attribute__((address_space(1))) void*)(unsigned long long)g,
      (__attribute__((address_space(3))) void*)l, 16, 0, 0);
}

// counted vmcnt wait; n is a compile-time constant after full unroll
DEV void vm_wait(int n) {
  switch (n) {
    case 0:  asm volatile("s_waitcnt vmcnt(0)" ::: "memory"); break;
    case 2:  asm volatile("s_waitcnt vmcnt(2)" ::: "memory"); break;
    case 4:  asm volatile("s_waitcnt vmcnt(4)" ::: "memory"); break;
    default: asm volatile("s_waitcnt vmcnt(6)" ::: "memory"); break;
  }
}

// ---------------------------------------------------------------------------
// K0b: convert w_qkv fp32 -> bf16
__global__ __launch_bounds__(256) void convert_w_kernel(
    const float* __restrict__ in, u16* __restrict__ out, int n) {
  int i = blockIdx.x * 256 + threadIdx.x;
  if (i < n) out[i] = f2bf(in[i]);
}

// ---------------------------------------------------------------------------
// B^T GEMM (131.7-µs R5 structure + LDS-restaged coalesced epilogue).
// C[j][m] = sum_k A^T[m][k]*B[j][k], K=192. BM=64, 4 waves (2m x 2n),
// 3 blocks/CU (48 KB LDS). A (64 px x 192 ch) staged once via fused
// transpose+convert at XOR-swizzled addresses; A-fragments hoisted to
// registers, after which sA is reused as 4 x 6 KB wave-private restage
// buffers so C stores issue as 64/128-B segments (2 instrs bf16 / 4 f32)
// instead of 16-row x 32-B scatter. j-loop per iter:
//   read B_j frags | lgkm+bar | prefetch B_{j+1} | restage+store acc(j-1)
//   | MFMA 24 | vmcnt(S)+bar     (S=2 bf16 / 4 f32; j=0 uses vmcnt(0))
template <bool IN_F32, bool OUT_BF16, int NJ>
__global__ __launch_bounds__(256, 3) void gemm_bt_kernel(
    const void* __restrict__ Av, const u16* __restrict__ B,
    void* __restrict__ Cv, size_t aBatch, size_t bBatch, size_t cBatch,
    int ldC) {
  __shared__ __align__(16) char smem[49152];
  char* sA = smem;            // [64][384B] content-swizzled; later restage
  char* sB = smem + 24576;    // [64][384B] content-swizzled

  const int tid = threadIdx.x, wave = tid >> 6, lane = tid & 63;
  const int id = blockIdx.x;
  const int m0 = (id & 255) * 64, b = id >> 8;
  const char* Bbase = (const char*)(B + (size_t)b * bBatch);
  constexpr int S = OUT_BF16 ? 2 : 4;  // store instrs per tile

  // ---- A-staging: fused transpose (+convert), swizzled ds_write
  if (IN_F32) {
    const float* Xb = (const float*)Av + (size_t)b * aBatch + m0;
    const int cbl = tid & 15, iq = tid >> 4;  // 16 c-quads x 16 n-quads
#pragma unroll
    for (int pass = 0; pass < 3; ++pass) {
      const int cb = pass * 16 + cbl;
      f32x4 v[4];
#pragma unroll
      for (int r = 0; r < 4; ++r)
        v[r] = *(const f32x4*)(Xb + (size_t)(cb * 4 + r) * 16384 + iq * 4);
#pragma unroll
      for (int j = 0; j < 4; ++j) {
        const int n = iq * 4 + j;
        u16x4 col;
        col[0] = f2bf(v[0][j]);
        col[1] = f2bf(v[1][j]);
        col[2] = f2bf(v[2][j]);
        col[3] = f2bf(v[3][j]);
        *(u16x4*)(sA + n * 384 + ((cb * 8) ^ ((n & 7) << 4))) = col;
      }
    }
  } else {
    const u16* Vb = (const u16*)Av + (size_t)b * aBatch + m0;
#pragma unroll
    for (int pass = 0; pass < 2; ++pass) {
      const int task = pass * 256 + tid;  // 48 c-quads x 8 n-octs = 384
      if (task < 384) {
        const int cb = task >> 3, io = task & 7;
        u16x8 v[4];
#pragma unroll
        for (int r = 0; r < 4; ++r)
          v[r] = *(const u16x8*)(Vb + (size_t)(cb * 4 + r) * 16384 + io * 8);
#pragma unroll
        for (int j = 0; j < 8; ++j) {
          const int n = io * 8 + j;
          u16x4 col;
          col[0] = v[0][j];
          col[1] = v[1][j];
          col[2] = v[2][j];
          col[3] = v[3][j];
          *(u16x4*)(sA + n * 384 + ((cb * 8) ^ ((n & 7) << 4))) = col;
        }
      }
    }
  }
  // ---- stage B_0 (24 KB, 6 chunks/wave)
#pragma unroll
  for (int i = 0; i < 6; ++i) {
    const int c = i * 4 + wave;
    const int d = c * 1024 + lane * 16;
    const int row = d / 384, inrow = d - row * 384;
    gload_lds16(Bbase + row * 384 + (inrow ^ ((row & 7) << 4)), sB + c * 1024);
  }
  asm volatile("s_waitcnt vmcnt(0) lgkmcnt(0)" ::: "memory");
  __builtin_amdgcn_s_barrier();

  const int wm = wave & 1, wn = wave >> 1;
  const int l15 = lane & 15, lg = lane >> 4;
  const int swm = (l15 & 7) << 4;
  const int rA0 = (wm * 32 + l15) * 384;
  const int rB0 = (wn * 32 + l15) * 384;

  // ---- A fragments to registers once; sA becomes dead
  bf16x8 af[2][6];
#pragma unroll
  for (int mi = 0; mi < 2; ++mi)
#pragma unroll
    for (int ks = 0; ks < 6; ++ks)
      af[mi][ks] = *(const bf16x8*)(sA + rA0 + mi * 16 * 384 +
                                    ((ks * 64 + lg * 16) ^ swm));
  asm volatile("s_waitcnt lgkmcnt(0)" ::: "memory");
  __builtin_amdgcn_s_barrier();  // all waves done with sA -> reusable

  char* rbuf = sA + wave * 6144;  // wave-private restage buffer

  // store tile j-1 (pack into rbuf, then coalesced segments)
  auto store_tile = [&](int j, const f32x4 acc[2][2]) {
    const int j0 = j * 64;
    if (OUT_BF16) {
#pragma unroll
      for (int mi = 0; mi < 2; ++mi)
#pragma unroll
        for (int nj = 0; nj < 2; ++nj) {
          u16x4 ov;
#pragma unroll
          for (int r = 0; r < 4; ++r) ov[r] = f2bf(acc[mi][nj][r]);
          *(u16x4*)(rbuf + (nj * 16 + l15) * 72 + mi * 32 + lg * 8) = ov;
        }
      asm volatile("s_waitcnt lgkmcnt(0)" ::: "memory");
      u16* Cb = (u16*)Cv + (size_t)b * cBatch;
#pragma unroll
      for (int q = 0; q < 2; ++q) {  // 2 instrs x 16 rows x 64 B
        const int flat = q * 64 + lane;
        const int row = flat >> 2;
        const u16x8 val = *(const u16x8*)(rbuf + row * 72 + (flat & 3) * 16);
        *(u16x8*)(Cb + (size_t)(j0 + wn * 32 + row) * ldC + m0 + wm * 32 +
                  (flat & 3) * 8) = val;
      }
    } else {
#pragma unroll
      for (int mi = 0; mi < 2; ++mi)
#pragma unroll
        for (int nj = 0; nj < 2; ++nj)
          *(f32x4*)(rbuf + (nj * 16 + l15) * 144 + mi * 64 + lg * 16) =
              acc[mi][nj];
      asm volatile("s_waitcnt lgkmcnt(0)" ::: "memory");
      float* Cb = (float*)Cv + (size_t)b * cBatch;
#pragma unroll
      for (int q = 0; q < 4; ++q) {  // 4 instrs x 8 rows x 128 B
        const int flat = q * 64 + lane;
        const int row = flat >> 3;
        const f32x4 val = *(const f32x4*)(rbuf + row * 144 + (flat & 7) * 16);
        *(f32x4*)(Cb + (size_t)(j0 + wn * 32 + row) * ldC + m0 + wm * 32 +
                  (flat & 7) * 4) = val;
      }
    }
  };

  f32x4 acc[2][2];
#pragma unroll
  for (int j = 0; j < NJ; ++j) {
    // read B_j fragments
    bf16x8 bfv[2][6];
#pragma unroll
    for (int nj = 0; nj < 2; ++nj)
#pragma unroll
      for (int ks = 0; ks < 6; ++ks)
        bfv[nj][ks] = *(const bf16x8*)(sB + rB0 + nj * 16 * 384 +
                                       ((ks * 64 + lg * 16) ^ swm));
    asm volatile("s_waitcnt lgkmcnt(0)" ::: "memory");
    __builtin_amdgcn_s_barrier();  // all waves consumed sB -> overwritable
    // prefetch B_{j+1} FIRST (so the end-of-iter wait covers it, not stores)
    if (j + 1 < NJ) {
      const char* Bj = Bbase + (size_t)(j + 1) * 24576;
#pragma unroll
      for (int i = 0; i < 6; ++i) {
        const int c = i * 4 + wave;
        const int d = c * 1024 + lane * 16;
        const int row = d / 384, inrow = d - row * 384;
        gload_lds16(Bj + row * 384 + (inrow ^ ((row & 7) << 4)), sB + c * 1024);
      }
    }
    if (j > 0) store_tile(j - 1, acc);
    __builtin_amdgcn_sched_barrier(0);  // pin: loads+stores issued before MFMA
#pragma unroll
    for (int mi = 0; mi < 2; ++mi)
#pragma unroll
      for (int nj = 0; nj < 2; ++nj) acc[mi][nj] = (f32x4){0.f, 0.f, 0.f, 0.f};
#pragma unroll
    for (int ks = 0; ks < 6; ++ks)
#pragma unroll
      for (int mi = 0; mi < 2; ++mi)
#pragma unroll
        for (int nj = 0; nj < 2; ++nj)
          acc[mi][nj] = __builtin_amdgcn_mfma_f32_16x16x32_bf16(
              af[mi][ks], bfv[nj][ks], acc[mi][nj], 0, 0, 0);
    if (j + 1 < NJ) {
      vm_wait(j == 0 ? 0 : S);  // B_{j+1} landed; this iter's stores ride on
      __builtin_amdgcn_s_barrier();
    }
  }
  store_tile(NJ - 1, acc);
}

// ---------------------------------------------------------------------------
// Depthwise 3x3 (pad 1), in-place on bf16 [b][576][128][128]; per-channel
// sum-of-squares for the q/k L2 norms. One block per (b, channel).
__global__ __launch_bounds__(256) void dwconv_kernel(
    u16* __restrict__ qkv, const float* __restrict__ wdw,
    float* __restrict__ sq) {
  __shared__ u16 img[16384];  // full 128x128 channel, 32 KB
  __shared__ float red[4];
  const int o = blockIdx.x, b = blockIdx.y;
  const size_t base = ((size_t)b * 576 + o) * 16384;
  const int tid = threadIdx.x, wave = tid >> 6, lane = tid & 63;
#pragma unroll
  for (int i = 0; i < 8; ++i) {
    const int off = (i * 4 + wave) * 1024;
    gload_lds16((const char*)qkv + base * 2 + off + lane * 16, (char*)img + off);
  }
  asm volatile("s_waitcnt vmcnt(0)" ::: "memory");
  __syncthreads();
  float w[9];
#pragma unroll
  for (int j = 0; j < 9; ++j) w[j] = wdw[o * 9 + j];
  float sqacc = 0.f;
  for (int it = 0; it < 8; ++it) {
    const int chunk = it * 256 + tid;  // 2048 chunks of 8 px
    const int px0 = chunk * 8;
    const int y = px0 >> 7, x0 = px0 & 127;
    float acc[8];
#pragma unroll
    for (int j = 0; j < 8; ++j) acc[j] = 0.f;
#pragma unroll
    for (int dy = -1; dy <= 1; ++dy) {
      const int yy = y + dy;
      float v[10];
      if (yy >= 0 && yy <= 127) {
        const u16* rowp = img + yy * 128 + x0;
        u16x8 m = *(const u16x8*)rowp;
#pragma unroll
        for (int j = 0; j < 8; ++j) v[j + 1] = bf2f(m[j]);
        v[0] = (x0 > 0) ? bf2f(rowp[-1]) : 0.f;
        v[9] = (x0 < 120) ? bf2f(rowp[8]) : 0.f;
      } else {
#pragma unroll
        for (int j = 0; j < 10; ++j) v[j] = 0.f;
      }
      const float w0 = w[(dy + 1) * 3], w1 = w[(dy + 1) * 3 + 1],
                  w2 = w[(dy + 1) * 3 + 2];
#pragma unroll
      for (int j = 0; j < 8; ++j) acc[j] += w0 * v[j] + w1 * v[j + 1] + w2 * v[j + 2];
    }
    u16x8 ov;
#pragma unroll
    for (int j = 0; j < 8; ++j) {
      sqacc += acc[j] * acc[j];
      ov[j] = f2bf(acc[j]);
    }
    *(u16x8*)(qkv + base + px0) = ov;  // in-place: all reads came from LDS
  }
#pragma unroll
  for (int s = 32; s > 0; s >>= 1) sqacc += __shfl_xor(sqacc, s, 64);
  if (lane == 0) red[wave] = sqacc;
  __syncthreads();
  if (tid == 0) sq[b * 576 + o] = red[0] + red[1] + red[2] + red[3];
}

// ---------------------------------------------------------------------------
// Gram: G_partial[c][d] = sum_n q[c][n]*k[d][n] over a 512-n block (4 waves x
// 128 n each, reduced in-block through LDS). Tile content XOR-swizzled.
// grid (32 chunk-groups, 16 bh); partial[bh][pos][chunk32].
__global__ __launch_bounds__(256) void gram_kernel(
    const u16* __restrict__ qkv, float* __restrict__ partial) {
  __shared__ u16 tiles[4 * 3072];   // per-wave [96][32] bf16 (q 0-47, k 48-95)
  __shared__ float red[4 * 2304];   // per-wave gram copies for in-block reduce
  const int bh = blockIdx.y, b = bh >> 2, h = bh & 3;
  const int g = blockIdx.x;                  // chunk 0..31
  const int wave = threadIdx.x >> 6, lane = threadIdx.x & 63;
  const int n0 = g * 512 + wave * 128;
  const u16* qb = qkv + ((size_t)b * 576 + h * 48) * 16384;
  const u16* kb = qb + (size_t)192 * 16384;
  char* tl = (char*)(tiles + wave * 3072);
  const int l15 = lane & 15, lg = lane >> 4;
  const int swz = (l15 & 3) << 4;
  f32x4 acc[3][3];
#pragma unroll
  for (int i = 0; i < 3; ++i)
#pragma unroll
    for (int j = 0; j < 3; ++j) acc[i][j] = (f32x4){0.f, 0.f, 0.f, 0.f};

  for (int ks = 0; ks < 4; ++ks) {
    const int nn = n0 + ks * 32;
    asm volatile("s_waitcnt lgkmcnt(0)" ::: "memory");
#pragma unroll
    for (int i = 0; i < 6; ++i) {
      const int flat = i * 1024 + lane * 16;
      const int row = flat >> 6, colb = flat & 63;
      const u16* src = (row < 48) ? (qb + (size_t)row * 16384 + nn)
                                  : (kb + (size_t)(row - 48) * 16384 + nn);
      gload_lds16((const char*)src + (colb ^ ((row & 3) << 4)), tl + i * 1024);
    }
    asm volatile("s_waitcnt vmcnt(0)" ::: "memory");
    bf16x8 qf[3], kf[3];
#pragma unroll
    for (int f = 0; f < 3; ++f) {
      qf[f] = *(const bf16x8*)(tl + (f * 16 + l15) * 64 + ((lg * 16) ^ swz));
      kf[f] = *(const bf16x8*)(tl + (48 + f * 16 + l15) * 64 + ((lg * 16) ^ swz));
    }
#pragma unroll
    for (int i = 0; i < 3; ++i)
#pragma unroll
      for (int j = 0; j < 3; ++j)
        acc[i][j] = __builtin_amdgcn_mfma_f32_16x16x32_bf16(qf[i], kf[j],
                                                            acc[i][j], 0, 0, 0);
  }
  // in-block reduce over the 4 waves
  {
    float* rw = red + wave * 2304;
#pragma unroll
    for (int i = 0; i < 3; ++i)
#pragma unroll
      for (int j = 0; j < 3; ++j)
#pragma unroll
        for (int r = 0; r < 4; ++r)
          rw[(i * 16 + lg * 4 + r) * 48 + (j * 16 + l15)] = acc[i][j][r];
  }
  __syncthreads();
#pragma unroll
  for (int it = 0; it < 9; ++it) {
    const int p = it * 256 + threadIdx.x;
    const float s = red[p] + red[2304 + p] + red[4608 + p] + red[6912 + p];
    partial[((size_t)bh * 2304 + p) * 32 + g] = s;
  }
}

// ---------------------------------------------------------------------------
// Stage 2: reduce 32 chunks (contiguous f32x4), normalize, softmax, fold
// attn into projection.
__global__ __launch_bounds__(256) void softmax_weff_kernel(
    const float* __restrict__ partial, const float* __restrict__ sq,
    const float* __restrict__ temp, const float* __restrict__ wproj,
    u16* __restrict__ weff) {
  __shared__ float G[2304];        // gram -> attn (in place)
  __shared__ float wp[192 * 49];   // wproj slice, pad 49 (odd bank stride)
  __shared__ float nq[48], nk[48];
  const int bh = blockIdx.x, b = bh >> 2, h = bh & 3;
  const int tid = threadIdx.x;
#pragma unroll
  for (int it = 0; it < 36; ++it) {  // load wproj [192][h*48 .. h*48+48)
    const int j = it * 256 + tid;
    const int o = j / 48, c = j - o * 48;
    wp[o * 49 + c] = wproj[o * 192 + h * 48 + c];
  }
#pragma unroll
  for (int it = 0; it < 9; ++it) {   // reduce 32 partial chunks, coalesced
    const int p = it * 256 + tid;
    const f32x4* pp = (const f32x4*)(partial + ((size_t)bh * 2304 + p) * 32);
    const f32x4 a = (pp[0] + pp[1]) + (pp[2] + pp[3]) +
                    (pp[4] + pp[5]) + (pp[6] + pp[7]);
    G[p] = a.x + a.y + a.z + a.w;
  }
  if (tid < 48) {
    nq[tid] = fmaxf(sqrtf(sq[b * 576 + h * 48 + tid]), 1e-12f);
    nk[tid] = fmaxf(sqrtf(sq[b * 576 + 192 + h * 48 + tid]), 1e-12f);
  }
  __syncthreads();
  if (tid < 48) {  // row softmax (48 rows)
    const int r = tid;
    const float inq = temp[h] / nq[r];
    float L[48];
    float mx = -3.4e38f;
#pragma unroll 4
    for (int d = 0; d < 48; ++d) {
      const float v = G[r * 48 + d] * inq / nk[d];
      L[d] = v;
      mx = fmaxf(mx, v);
    }
    float s = 0.f;
#pragma unroll 4
    for (int d = 0; d < 48; ++d) {
      const float e = __expf(L[d] - mx);
      L[d] = e;
      s += e;
    }
    const float inv = 1.f / s;
#pragma unroll 4
    for (int d = 0; d < 48; ++d) G[r * 48 + d] = L[d] * inv;
  }
  __syncthreads();
  if (tid < 192) {  // Weff row o = tid
    const int o = tid;
    f32x4 acc[12];
#pragma unroll
    for (int dv = 0; dv < 12; ++dv) acc[dv] = (f32x4){0.f, 0.f, 0.f, 0.f};
    for (int c = 0; c < 48; ++c) {
      const float w = wp[o * 49 + c];
      const f32x4* at = (const f32x4*)(G + c * 48);  // broadcast reads
#pragma unroll
      for (int dv = 0; dv < 12; ++dv) acc[dv] += w * at[dv];
    }
    u16* op = weff + ((size_t)b * 192 + o) * 192 + h * 48;
#pragma unroll
    for (int g8 = 0; g8 < 6; ++g8) {
      u16x8 ov;
#pragma unroll
      for (int j = 0; j < 8; ++j) {
        const int d = g8 * 8 + j;
        ov[j] = f2bf(acc[d >> 2][d & 3]);
      }
      *(u16x8*)(op + g8 * 8) = ov;
    }
  }
}

// ---------------------------------------------------------------------------
extern "C" void kernel_launch(void* const* d_in, const int* in_sizes, int n_in,
                              void* d_out, int out_size, void* d_ws,
                              size_t ws_size, hipStream_t stream) {
  (void)in_sizes; (void)n_in; (void)out_size; (void)ws_size;
  const float* x      = (const float*)d_in[0];  // [4][192][128][128]
  const float* w_qkv  = (const float*)d_in[1];  // [576][192]
  const float* w_dw   = (const float*)d_in[2];  // [576][9]
  const float* w_proj = (const float*)d_in[3];  // [192][192]
  const float* temp   = (const float*)d_in[4];  // [4]

  char* ws = (char*)d_ws;
  u16*   qkv     = (u16*)ws;                    // 75,497,472 B
  float* partial = (float*)(ws + 75497472);     //  4,718,592 B [16][2304][32]
  float* sq      = (float*)(ws + 80216064);     //      9,216 B
  u16*   Wq      = (u16*)(ws + 80225280);       //    221,184 B [576][192]
  u16*   Weff    = (u16*)(ws + 80446464);       //    294,912 B [4][192][192]

  // w_qkv -> bf16
  convert_w_kernel<<<dim3(432), 256, 0, stream>>>(w_qkv, Wq, 110592);
  // qkv[b][o][n] = sum_c x[c][n]*Wq[o][c]  (fused x-transpose in staging)
  gemm_bt_kernel<true, true, 9><<<dim3(1024), 256, 0, stream>>>(
      x, Wq, qkv, (size_t)192 * 16384, 0, (size_t)576 * 16384, 16384);
  // depthwise 3x3 in-place + per-channel sum-of-squares
  dwconv_kernel<<<dim3(576, 4), 256, 0, stream>>>(qkv, w_dw, sq);
  // gram partials: 32 chunk-groups per (b,h), in-block wave reduction
  gram_kernel<<<dim3(32, 16), 256, 0, stream>>>(qkv, partial);
  // reduce + normalize + softmax + fold into projection
  softmax_weff_kernel<<<dim3(16), 256, 0, stream>>>(partial, sq, temp, w_proj,
                                                    Weff);
  // out[b][o][n] = sum_c2 v[c2][n]*Weff[o][c2] (fused v-transpose in staging)
  gemm_bt_kernel<false, false, 3><<<dim3(1024), 256, 0, stream>>>(
      qkv + (size_t)384 * 16384, Weff, d_out, (size_t)576 * 16384,
      (size_t)192 * 192, (size_t)192 * 16384, 16384);
}